// Round 9
// baseline (141.225 us; speedup 1.0000x reference)
//
#include <hip/hip_runtime.h>
#include <hip/hip_bf16.h>

// NeighbourhoodAttnBlock: B=2, H=W=64, D=512, NH=8, DH=64, KERNEL=7
// Inputs fp32; output fp32. Internal pipeline bf16 MFMA.
// Stage 0: tiny weight-only fp32->bf16 cvt (w_qkv, w_out)
// Stage 1: qkv GEMM with fused x fp32->bf16 in A-staging (reg cvt + ds_write,
//          padded LDS); W via global_load_lds. -> q,k [bh][s][dh]; vt [bh][dh][s]
// Stage 2: MFMA neighbourhood attention (R7 structure: 4-wave block per
//          (bh, 8x8 query tile), K and V windows staged in LDS)
// Stage 3: out GEMM (LDS-staged, BN=64) -> d_out (fp32)

typedef __bf16 bf16x8 __attribute__((ext_vector_type(8)));
typedef __bf16 bf16x4 __attribute__((ext_vector_type(4)));
typedef float  f32x4  __attribute__((ext_vector_type(4)));

__global__ __launch_bounds__(256) void cvt_w(
    const float* __restrict__ wq, const float* __restrict__ wo,
    __bf16* __restrict__ wqb, __bf16* __restrict__ wob) {
  int i = blockIdx.x * 256 + threadIdx.x;  // 262144 f32x4 chunks total
  const float* src;
  __bf16* dst;
  int j = i;
  if (j < 196608) {
    src = wq; dst = wqb;
  } else {
    j -= 196608; src = wo; dst = wob;
  }
  f32x4 v = ((const f32x4*)src)[j];
  bf16x4 o;
  o[0] = (__bf16)v[0]; o[1] = (__bf16)v[1];
  o[2] = (__bf16)v[2]; o[3] = (__bf16)v[3];
  ((bf16x4*)dst)[j] = o;
}

__device__ __forceinline__ void gload_lds16(const __bf16* g, __bf16* l) {
  __builtin_amdgcn_global_load_lds(
      (const __attribute__((address_space(1))) void*)g,
      (__attribute__((address_space(3))) void*)l, 16, 0, 0);
}

// QKV GEMM with fused A conversion.
// C[i][e] = sum_d x[i][d] * W[e][d]; x fp32 [8192,512], W bf16 [1536,512].
// 128x128 tile, 4 waves x 64x64, BK=32. A: fp32 global -> reg cvt ->
// ds_write_b128 into padded Al[128][36] (conflict-free b128 starts).
__global__ __launch_bounds__(256, 3) void gemm_qkv(
    const float* __restrict__ A, const __bf16* __restrict__ W,
    __bf16* __restrict__ qo, __bf16* __restrict__ ko, __bf16* __restrict__ vo,
    int etiles) {
  constexpr int K = 512;
  __shared__ alignas(16) __bf16 Al[128][36];
  __shared__ alignas(16) __bf16 Wl[128 * 32];
  const int tid = threadIdx.x;
  const int wv = tid >> 6, lane = tid & 63;
  const int n16 = lane & 15, quad = lane >> 4;
  const int bi = blockIdx.x / etiles, be = blockIdx.x % etiles;
  const int i0 = bi << 7, e0 = be << 7;
  const int wm = (wv & 1) << 6, we = (wv >> 1) << 6;

  // A staging: thread covers row tid/2, 16-float half tid&1
  const int arow = tid >> 1, ahalf = tid & 1;
  const float* gA = A + (size_t)(i0 + arow) * K + ahalf * 16;
  // W staging (bf16, global_load_lds)
  const int srow = (wv << 4) + (lane >> 2);
  const int scol = (lane & 3) << 3;
  const __bf16* gW = W + (size_t)(e0 + srow) * K + scol;
  __bf16* lW = &Wl[(wv << 9) + (lane << 3)];

  f32x4 acc[4][4];
#pragma unroll
  for (int a = 0; a < 4; ++a)
#pragma unroll
    for (int b = 0; b < 4; ++b) acc[a][b] = (f32x4){0.f, 0.f, 0.f, 0.f};

  f32x4 a4[4];
#pragma unroll
  for (int j = 0; j < 4; ++j) a4[j] = *(const f32x4*)(gA + j * 4);

  for (int k0 = 0; k0 < K; k0 += 32) {
    // cvt current A regs -> two bf16x8
    bf16x8 ab0, ab1;
#pragma unroll
    for (int j = 0; j < 4; ++j) {
      ab0[j] = (__bf16)a4[0][j]; ab0[j + 4] = (__bf16)a4[1][j];
      ab1[j] = (__bf16)a4[2][j]; ab1[j + 4] = (__bf16)a4[3][j];
    }
    if (k0) __syncthreads();  // prev iter's LDS reads done
    *(bf16x8*)&Al[arow][ahalf * 16] = ab0;
    *(bf16x8*)&Al[arow][ahalf * 16 + 8] = ab1;
    gload_lds16(gW + k0, lW);
    gload_lds16(gW + (size_t)64 * K + k0, lW + 64 * 32);
    if (k0 + 32 < K) {  // prefetch next A
#pragma unroll
      for (int j = 0; j < 4; ++j)
        a4[j] = *(const f32x4*)(gA + k0 + 32 + j * 4);
    }
    __syncthreads();  // staging visible

    bf16x8 af[4], wf[4];
#pragma unroll
    for (int t = 0; t < 4; ++t) {
      af[t] = *(const bf16x8*)&Al[wm + t * 16 + n16][quad * 8];
      wf[t] = *(const bf16x8*)&Wl[(we + t * 16 + n16) * 32 + quad * 8];
    }
#pragma unroll
    for (int mt = 0; mt < 4; ++mt)
#pragma unroll
      for (int nt = 0; nt < 4; ++nt)
        acc[mt][nt] = __builtin_amdgcn_mfma_f32_16x16x32_bf16(
            af[mt], wf[nt], acc[mt][nt], 0, 0, 0);
  }

  // epilogue: per-(mt,nt) constants hoisted
#pragma unroll
  for (int mt = 0; mt < 4; ++mt)
#pragma unroll
    for (int nt = 0; nt < 4; ++nt) {
      f32x4 f = acc[mt][nt];
      int e = e0 + we + nt * 16 + n16;
      int t = e >> 9, head = (e >> 6) & 7, dh = e & 63;
      int ib = i0 + wm + mt * 16 + quad * 4;  // 4 consecutive rows, same b
      int b = ib >> 12, s = ib & 4095;
      int bh = b * 8 + head;
      if (t == 2) {
        __bf16* p = vo + ((size_t)bh * 64 + dh) * 4096 + s;  // stride 1 in rg
#pragma unroll
        for (int rg = 0; rg < 4; ++rg) p[rg] = (__bf16)f[rg];
      } else {
        __bf16* p = ((t == 0) ? qo : ko) + ((size_t)bh * 4096 + s) * 64 + dh;
#pragma unroll
        for (int rg = 0; rg < 4; ++rg) p[rg * 64] = (__bf16)f[rg];
      }
    }
}

// out GEMM: C[i][e] = sum_d ao[i][d] * W[e][d]; both bf16, out fp32.
// 128x64 tile, 4 waves x 64x32, BK=32, global_load_lds staging.
__global__ __launch_bounds__(256, 3) void gemm_out(
    const __bf16* __restrict__ A, const __bf16* __restrict__ W,
    float* __restrict__ co, int etiles) {
  constexpr int K = 512;
  __shared__ alignas(16) __bf16 Al[128 * 32];
  __shared__ alignas(16) __bf16 Wl[64 * 32];
  const int tid = threadIdx.x;
  const int wv = tid >> 6, lane = tid & 63;
  const int n16 = lane & 15, quad = lane >> 4;
  const int bi = blockIdx.x / etiles, be = blockIdx.x % etiles;
  const int i0 = bi << 7, e0 = be << 6;
  const int wm = (wv & 1) << 6, we = (wv >> 1) << 5;

  const int srow = (wv << 4) + (lane >> 2);
  const int scol = (lane & 3) << 3;
  const __bf16* gA = A + (size_t)(i0 + srow) * K + scol;
  const __bf16* gW = W + (size_t)(e0 + srow) * K + scol;
  __bf16* lA = &Al[(wv << 9) + (lane << 3)];
  __bf16* lW = &Wl[(wv << 9) + (lane << 3)];

  f32x4 acc[4][2];
#pragma unroll
  for (int a = 0; a < 4; ++a)
#pragma unroll
    for (int b = 0; b < 2; ++b) acc[a][b] = (f32x4){0.f, 0.f, 0.f, 0.f};

  for (int k0 = 0; k0 < K; k0 += 32) {
    if (k0) __syncthreads();
    gload_lds16(gA + k0, lA);
    gload_lds16(gA + (size_t)64 * K + k0, lA + 64 * 32);
    gload_lds16(gW + k0, lW);
    __syncthreads();

    bf16x8 af[4], wf[2];
#pragma unroll
    for (int t = 0; t < 4; ++t)
      af[t] = *(const bf16x8*)&Al[(wm + t * 16 + n16) * 32 + quad * 8];
#pragma unroll
    for (int t = 0; t < 2; ++t)
      wf[t] = *(const bf16x8*)&Wl[(we + t * 16 + n16) * 32 + quad * 8];
#pragma unroll
    for (int mt = 0; mt < 4; ++mt)
#pragma unroll
      for (int nt = 0; nt < 2; ++nt)
        acc[mt][nt] = __builtin_amdgcn_mfma_f32_16x16x32_bf16(
            af[mt], wf[nt], acc[mt][nt], 0, 0, 0);
  }

#pragma unroll
  for (int mt = 0; mt < 4; ++mt)
#pragma unroll
    for (int nt = 0; nt < 2; ++nt) {
      f32x4 f = acc[mt][nt];
      int e = e0 + we + nt * 16 + n16;
      int ib = i0 + wm + mt * 16 + quad * 4;
      float* p = co + (size_t)ib * 512 + e;
#pragma unroll
      for (int rg = 0; rg < 4; ++rg) p[rg * 512] = f[rg];
    }
}

// MFMA neighbourhood attention (R7 structure). One workgroup per
// (bh, 8x8 query tile). Phase 1: coop-load K-window (14x16 keys x 64 dh,
// xor-swizzled) into r1; QK^T via ds_read_b128; softmax in regs; P -> sbuf.
// Phase 2: barrier; coop-load V-window into r1 as vwin[dh][232]; PV from LDS.
__global__ __launch_bounds__(256) void attn_mfma(
    const __bf16* __restrict__ q, const __bf16* __restrict__ k,
    const __bf16* __restrict__ vt, __bf16* __restrict__ out) {
  __shared__ alignas(16) __bf16 r1[14848];         // kwin / vwin[64][232]
  __shared__ alignas(16) __bf16 sbuf[4][16][232];  // per-wave P (padded)
  const int tid = threadIdx.x;
  const int wv = tid >> 6;
  const int lane = tid & 63;
  const int n16 = lane & 15, quad = lane >> 4;
  const int bh = blockIdx.x >> 6;
  const int tile = blockIdx.x & 63;
  const int qh0 = (tile >> 3) << 3, qw0 = (tile & 7) << 3;
  int wh0 = qh0 - 3; wh0 = wh0 < 0 ? 0 : (wh0 > 50 ? 50 : wh0);
  int wc0 = qw0 - 3; wc0 = wc0 < 0 ? 0 : (wc0 > 48 ? 48 : wc0);
  wc0 &= ~1;  // -> multiple of 4; window covers [qw0-3, qw0+10]
  const size_t base = (size_t)bh * 4096 * 64;

  // ---- Q A-frags (issue first; fly during coop K load) ----
  const int qi_a = wv * 16 + n16;
  const int sqa = (qh0 + (qi_a >> 3)) * 64 + qw0 + (qi_a & 7);
  const __bf16* qp = q + base + (size_t)sqa * 64 + quad * 8;
  bf16x8 aq0 = *(const bf16x8*)qp;
  bf16x8 aq1 = *(const bf16x8*)(qp + 32);

  // ---- coop load K window: 14 rows x 2 KB contiguous each ----
  const __bf16* kbase = k + base;
#pragma unroll
  for (int i = 0; i < 7; ++i) {
    int ch = i * 256 + tid;           // 1792 16-B chunks
    int kr = ch >> 7, wi = ch & 127;
    int kc = wi >> 3, dh8 = wi & 7;
    bf16x8 d = *(const bf16x8*)(kbase +
        (size_t)((wh0 + kr) * 64 + wc0 + kc) * 64 + dh8 * 8);
    *(bf16x8*)&r1[(kr * 16 + kc) * 64 + ((dh8 ^ (kc & 7)) * 8)] = d;
  }
  __syncthreads();

  // ---- scores from LDS ----
  f32x4 S[14];
  const int skw = wc0 + n16;
  const int sw1 = ((quad ^ (n16 & 7)) * 8);
  const int sw2 = (((4 + quad) ^ (n16 & 7)) * 8);
#pragma unroll
  for (int nt = 0; nt < 14; ++nt) {
    int key = nt * 16 + n16;
    bf16x8 b0 = *(const bf16x8*)&r1[key * 64 + sw1];
    bf16x8 b1 = *(const bf16x8*)&r1[key * 64 + sw2];
    f32x4 s = {0.f, 0.f, 0.f, 0.f};
    s = __builtin_amdgcn_mfma_f32_16x16x32_bf16(aq0, b0, s, 0, 0, 0);
    s = __builtin_amdgcn_mfma_f32_16x16x32_bf16(aq1, b1, s, 0, 0, 0);
    S[nt] = s;
  }

  // ---- exact mask + scale + row max ----
  float mx[4] = {-1e30f, -1e30f, -1e30f, -1e30f};
#pragma unroll
  for (int reg = 0; reg < 4; ++reg) {
    int qi = wv * 16 + quad * 4 + reg;
    int qh = qh0 + (qi >> 3), qw = qw0 + (qi & 7);
    int sh = qh - 3; sh = sh < 0 ? 0 : (sh > 57 ? 57 : sh);
    int sw = qw - 3; sw = sw < 0 ? 0 : (sw > 57 ? 57 : sw);
    bool wok = (skw >= sw) && (skw < sw + 7);
#pragma unroll
    for (int nt = 0; nt < 14; ++nt) {
      int kh = wh0 + nt;
      bool ok = wok && (kh >= sh) && (kh < sh + 7);
      float val = ok ? S[nt][reg] * 0.125f : -1e30f;
      S[nt][reg] = val;
      mx[reg] = mx[reg] > val ? mx[reg] : val;
    }
  }
#pragma unroll
  for (int reg = 0; reg < 4; ++reg)
#pragma unroll
    for (int off = 8; off >= 1; off >>= 1) {
      float o = __shfl_xor(mx[reg], off);
      mx[reg] = mx[reg] > o ? mx[reg] : o;
    }

  // ---- exp + row sum ----
  float sm[4] = {0.f, 0.f, 0.f, 0.f};
#pragma unroll
  for (int nt = 0; nt < 14; ++nt)
#pragma unroll
    for (int reg = 0; reg < 4; ++reg) {
      float p = __expf(S[nt][reg] - mx[reg]);
      S[nt][reg] = p;
      sm[reg] += p;
    }
#pragma unroll
  for (int reg = 0; reg < 4; ++reg)
#pragma unroll
    for (int off = 8; off >= 1; off >>= 1) sm[reg] += __shfl_xor(sm[reg], off);

  // ---- P -> per-wave LDS region ----
#pragma unroll
  for (int reg = 0; reg < 4; ++reg) {
    float inv = 1.f / sm[reg];
    int row = quad * 4 + reg;
#pragma unroll
    for (int nt = 0; nt < 14; ++nt)
      sbuf[wv][row][nt * 16 + n16] = (__bf16)(S[nt][reg] * inv);
  }

  __syncthreads();  // all waves done reading kwin
  // ---- coop load V window into vwin[dh][232] (key = kr*16+kc) ----
  const __bf16* vtb = vt + base;
#pragma unroll
  for (int i = 0; i < 7; ++i) {
    int c = i * 256 + tid;  // 1792 16-B chunks: c = dh*28 + kr*2 + half
    int dh = c / 28, rem = c % 28;
    int kr = rem >> 1, half = rem & 1;
    bf16x8 d = *(const bf16x8*)(vtb + (size_t)dh * 4096 +
                                (wh0 + kr) * 64 + wc0 + half * 8);
    *(bf16x8*)&r1[dh * 232 + kr * 16 + half * 8] = d;
  }
  __syncthreads();

  // ---- PV: O[16q x 64dh] = P(16x224) . V_win(224x64), all LDS ----
  f32x4 O[4] = {{0.f, 0.f, 0.f, 0.f},
                {0.f, 0.f, 0.f, 0.f},
                {0.f, 0.f, 0.f, 0.f},
                {0.f, 0.f, 0.f, 0.f}};
#pragma unroll
  for (int kt = 0; kt < 7; ++kt) {
    bf16x8 pa = *(const bf16x8*)&sbuf[wv][n16][kt * 32 + quad * 8];
    int key0 = kt * 32 + quad * 8;
#pragma unroll
    for (int ntv = 0; ntv < 4; ++ntv) {
      bf16x8 vb = *(const bf16x8*)&r1[(ntv * 16 + n16) * 232 + key0];
      O[ntv] = __builtin_amdgcn_mfma_f32_16x16x32_bf16(pa, vb, O[ntv], 0, 0, 0);
    }
  }

  // ---- epilogue: ao[b][s][head*64+dh] bf16 ----
  const int b = bh >> 3, head = bh & 7;
#pragma unroll
  for (int ntv = 0; ntv < 4; ++ntv)
#pragma unroll
    for (int reg = 0; reg < 4; ++reg) {
      int qi = wv * 16 + quad * 4 + reg;
      int s_q = (qh0 + (qi >> 3)) * 64 + qw0 + (qi & 7);
      int dh = ntv * 16 + n16;
      out[((size_t)(b * 4096 + s_q)) * 512 + head * 64 + dh] =
          (__bf16)O[ntv][reg];
    }
}

extern "C" void kernel_launch(void* const* d_in, const int* in_sizes, int n_in,
                              void* d_out, int out_size, void* d_ws,
                              size_t ws_size, hipStream_t stream) {
  const float* x = (const float*)d_in[0];      // [2,64,64,512] fp32
  const float* w_qkv = (const float*)d_in[1];  // [1536,512] fp32
  const float* w_out = (const float*)d_in[2];  // [512,512] fp32
  float* out = (float*)d_out;                  // [2,64,64,512] fp32

  const size_t qelems = (size_t)2 * 8 * 4096 * 64;  // 4,194,304
  __bf16* q = (__bf16*)d_ws;
  __bf16* k = q + qelems;
  __bf16* vt = k + qelems;          // V transposed [bh][dh][s]
  __bf16* ao = vt + qelems;         // attn out [8192,512]
  __bf16* wqb = ao + qelems;        // converted w_qkv
  __bf16* wob = wqb + 1536 * 512;   // converted w_out

  // Stage 0: weight-only fp32 -> bf16 (262144 f32x4 chunks)
  cvt_w<<<dim3(1024), dim3(256), 0, stream>>>(w_qkv, w_out, wqb, wob);

  // Stage 1: QKV GEMM (fused x cvt): 64 i-tiles x 12 e-tiles = 768 blocks
  gemm_qkv<<<dim3(768), dim3(256), 0, stream>>>(x, wqb, q, k, vt, 12);
  // Stage 2: MFMA attention: 16 bh * 64 tiles = 1024 workgroups
  attn_mfma<<<dim3(1024), dim3(256), 0, stream>>>(q, k, vt, ao);
  // Stage 3: out GEMM: 64 i-tiles x 8 e-tiles = 512 blocks
  gemm_out<<<dim3(512), dim3(256), 0, stream>>>(ao, wob, out, 8);
}